// Round 14
// baseline (420.345 us; speedup 1.0000x reference)
//
#include <hip/hip_runtime.h>

// TransformerBlock on MI355X (gfx950). fp32 I/O, bf16 MFMA compute.
// B=2 S=2048 D=1024 H=16 Dh=64 HIDDEN=4096, causal, exact GELU.
//
// Round 19: R18 = 419us champion (packed operands + LDS-staged packed C
// fixed the whole GEMM tier; all GEMMs now <83us). New #1: attn at 82.7us,
// MfmaUtil 8.4 / VALUBusy 45 / Occupancy 13% -> VALU-bound + occupancy-
// starved (66.5KB LDS = 2 blocks/CU). Fix: revert attn K/V staging to the
// R5-verified 2-buffer __syncthreads loop (R14's 3-buf pipe measured null)
// -> LDS 49.4KB -> 3 blocks/CU, 12 waves. Everything else identical.
// Packed element (m,k), K-depth: addr = ((m>>4)*(K>>5)+(k>>5))*512
//                                     + ((k&31)>>3)*128 + (m&15)*8 + (k&7).
// Workspace (80 MB):
//   [ 0, 6M) wqkv^T  [ 6, 8M) wo^T  [ 8,16M) w1^T  [16,24M) w2^T
//   [24,32M) h -> vt (V^T) -> h2    [32,56M) qkv -> g(32MB spans [32,64M))
//   [56,64M) ctx     [64,80M) x1 (fp32)

typedef __bf16 bf16x8_t __attribute__((ext_vector_type(8)));
typedef float f32x4_t __attribute__((ext_vector_type(4)));
typedef unsigned short u16x8 __attribute__((ext_vector_type(8)));

__device__ __forceinline__ unsigned short f2b(float f) {
    unsigned int u = __builtin_bit_cast(unsigned int, f);
    u += 0x7fffu + ((u >> 16) & 1u);   // round-to-nearest-even
    return (unsigned short)(u >> 16);
}
__device__ __forceinline__ bf16x8_t as_bf(u16x8 v) {
    return __builtin_bit_cast(bf16x8_t, v);
}
__device__ __forceinline__ void store_out(float* p, float v) { *p = v; }
__device__ __forceinline__ void store_out(unsigned short* p, float v) { *p = f2b(v); }

// packed-subtile index: element (m,k) of an [M][K] bf16 operand
__device__ __forceinline__ size_t pidx(int m, int k, int K) {
    return (((size_t)((m >> 4) * (K >> 5) + (k >> 5))) << 9) +
           (((k & 31) >> 3) << 7) + ((m & 15) << 3) + (k & 7);
}

// async global->LDS, 16B per lane; lds dest must be wave-uniform base
__device__ __forceinline__ void glds16(const unsigned short* g, unsigned short* l) {
    __builtin_amdgcn_global_load_lds(
        (const __attribute__((address_space(1))) unsigned int*)g,
        (__attribute__((address_space(3))) unsigned int*)l, 16, 0, 0);
}

template <int N>
__device__ __forceinline__ void wait_vm() {
    asm volatile("s_waitcnt vmcnt(%0)" ::"i"(N) : "memory");
}

// -------------------------------------------------- transpose + cast weights
// src [K][N] fp32 -> packed B (element (n,k) = src[k][n]), K-depth = K
__global__ __launch_bounds__(256) void transpose_cast(
    const float* __restrict__ src, unsigned short* __restrict__ dst,
    int K, int N) {
    __shared__ float tile[32][33];
    const int k0 = blockIdx.x * 32, n0 = blockIdx.y * 32;
    const int c = threadIdx.x & 31, r8 = threadIdx.x >> 5;
#pragma unroll
    for (int i = 0; i < 4; i++) {
        const int r = r8 + i * 8;
        tile[r][c] = src[(size_t)(k0 + r) * N + n0 + c];
    }
    __syncthreads();
#pragma unroll
    for (int i = 0; i < 4; i++) {
        const int rr = r8 + i * 8;
        dst[pidx(n0 + rr, k0 + c, K)] = f2b(tile[c][rr]);
    }
}

// four 1024x1024 weight transposes batched (wq,wk,wv -> wqkvt; wo -> wot), packed
__global__ __launch_bounds__(256) void transpose_cast4(
    const float* __restrict__ s0, const float* __restrict__ s1,
    const float* __restrict__ s2, const float* __restrict__ s3,
    unsigned short* __restrict__ wqkvt, unsigned short* __restrict__ wot) {
    __shared__ float tile[32][33];
    const int z = blockIdx.z;
    const float* src = (z == 0) ? s0 : (z == 1) ? s1 : (z == 2) ? s2 : s3;
    unsigned short* dst = (z < 3) ? wqkvt + ((size_t)z << 20) : wot;
    const int k0 = blockIdx.x * 32, n0 = blockIdx.y * 32;
    const int c = threadIdx.x & 31, r8 = threadIdx.x >> 5;
#pragma unroll
    for (int i = 0; i < 4; i++) {
        const int r = r8 + i * 8;
        tile[r][c] = src[(size_t)(k0 + r) * 1024 + n0 + c];
    }
    __syncthreads();
#pragma unroll
    for (int i = 0; i < 4; i++) {
        const int rr = r8 + i * 8;
        dst[pidx(n0 + rr, k0 + c, 1024)] = f2b(tile[c][rr]);
    }
}

// -------------------------------------------------- V -> V^T packed per (b,head)
// src: qkv V columns (rows of 3072-stride). dst: panel (b*16+h) of [64][2048],
// packed subtiles (K-depth 2048). panel stride 64*2048 = 1<<17.
__global__ __launch_bounds__(256) void vtrans_kernel(
    const unsigned short* __restrict__ src, unsigned short* __restrict__ dst) {
    __shared__ unsigned short tile[32][34];
    const int s0 = blockIdx.x * 32, hd0 = blockIdx.y * 32, b = blockIdx.z;
    const int c = threadIdx.x & 31, r8 = threadIdx.x >> 5;
#pragma unroll
    for (int i = 0; i < 4; i++) {
        const int r = r8 + i * 8;
        tile[r][c] = src[(size_t)(b * 2048 + s0 + r) * 3072 + hd0 + c];
    }
    __syncthreads();
#pragma unroll
    for (int i = 0; i < 4; i++) {
        const int rr = r8 + i * 8;
        const int g = b * 1024 + hd0 + rr;        // global hd row
        const int panel = g >> 6, local = g & 63;
        dst[((size_t)panel << 17) + pidx(local, s0 + c, 2048)] = tile[c][rr];
    }
}

// ---------------------------------------------------------------- LayerNorm
// output PACKED (K-depth 1024) - consumed only by GEMM A-staging.
__global__ __launch_bounds__(256) void ln_kernel(
    const float* __restrict__ X,
    const float* __restrict__ scale,
    const float* __restrict__ shift,
    unsigned short* __restrict__ Hout) {
    const int tok = blockIdx.x;
    const int tid = threadIdx.x;
    const size_t base = (size_t)tok * 1024 + tid * 4;
    float4 xv = *(const float4*)(X + base);
    float f[4] = {xv.x, xv.y, xv.z, xv.w};
    float s = 0.f, s2 = 0.f;
#pragma unroll
    for (int i = 0; i < 4; i++) { s += f[i]; s2 += f[i] * f[i]; }
#pragma unroll
    for (int off = 32; off >= 1; off >>= 1) {
        s += __shfl_down(s, off);
        s2 += __shfl_down(s2, off);
    }
    __shared__ float red[8];
    const int wv = tid >> 6;
    if ((tid & 63) == 0) { red[wv] = s; red[4 + wv] = s2; }
    __syncthreads();
    s = red[0] + red[1] + red[2] + red[3];
    s2 = red[4] + red[5] + red[6] + red[7];
    const float mean = s * (1.f / 1024.f);
    const float var = s2 * (1.f / 1024.f) - mean * mean;
    const float rstd = rsqrtf(var + 1e-5f);
    const float4 sc = *(const float4*)(scale + tid * 4);
    const float4 sh = *(const float4*)(shift + tid * 4);
    unsigned short ov[4];
    ov[0] = f2b((f[0] - mean) * rstd * sc.x + sh.x);
    ov[1] = f2b((f[1] - mean) * rstd * sc.y + sh.y);
    ov[2] = f2b((f[2] - mean) * rstd * sc.z + sh.z);
    ov[3] = f2b((f[3] - mean) * rstd * sc.w + sh.w);
    *(unsigned long long*)(Hout + pidx(tok, tid * 4, 1024)) = *(unsigned long long*)ov;
}

// ---------------------------------------------------------------- GEMM (2-barrier)
// A, Bt PACKED. EPI: 1 = bias + residual (res row-major fp32).
template <int BN, int EPI, typename OutT>
__global__ __launch_bounds__(256) void gemm_kernel(
    const unsigned short* __restrict__ A, const unsigned short* __restrict__ Bt,
    const float* __restrict__ bias, const float* __restrict__ res,
    OutT* __restrict__ C, int M, int N, int K) {
    constexpr int BSUB = BN / 16;
    constexpr int JF = BN / 32;
    __shared__ __align__(16) unsigned short As[2][8 * 512];
    __shared__ __align__(16) unsigned short Bs[2][BSUB * 512];
    const int tid = threadIdx.x;
    const int w = tid >> 6, lane = tid & 63;
    const int quad = lane >> 4, l16 = lane & 15;
    const int bm = blockIdx.x * 128, bn = blockIdx.y * BN;
    const int wm = (w & 1) * 64, wn = (w >> 1) * (BN / 2);
    const int KT = K >> 5;

    f32x4_t acc[4][JF];
#pragma unroll
    for (int i = 0; i < 4; i++)
#pragma unroll
        for (int j = 0; j < JF; j++) acc[i][j] = f32x4_t{0.f, 0.f, 0.f, 0.f};

    // packed: subtile s at k-tile kt is one contiguous 1KB block
    const unsigned short* Ab = A + (((size_t)(bm >> 4) * KT) << 9) + lane * 8;
    const unsigned short* Bb = Bt + (((size_t)(bn >> 4) * KT) << 9) + lane * 8;

    {
        for (int s = w; s < 8; s += 4)
            glds16(Ab + ((size_t)(s * KT) << 9), &As[0][s * 512]);
        for (int s = w; s < BSUB; s += 4)
            glds16(Bb + ((size_t)(s * KT) << 9), &Bs[0][s * 512]);
    }
    __syncthreads();

    int buf = 0;
    for (int kt = 0; kt < KT; ++kt) {
        if (kt + 1 < KT) {
            for (int s = w; s < 8; s += 4)
                glds16(Ab + ((size_t)(s * KT + kt + 1) << 9), &As[buf ^ 1][s * 512]);
            for (int s = w; s < BSUB; s += 4)
                glds16(Bb + ((size_t)(s * KT + kt + 1) << 9), &Bs[buf ^ 1][s * 512]);
        }
        bf16x8_t af[4], bfv[JF];
#pragma unroll
        for (int i = 0; i < 4; i++)
            af[i] = as_bf(*(const u16x8*)&As[buf][((wm >> 4) + i) * 512 + lane * 8]);
#pragma unroll
        for (int j = 0; j < JF; j++)
            bfv[j] = as_bf(*(const u16x8*)&Bs[buf][((wn >> 4) + j) * 512 + lane * 8]);
#pragma unroll
        for (int i = 0; i < 4; i++)
#pragma unroll
            for (int j = 0; j < JF; j++)
                acc[i][j] = __builtin_amdgcn_mfma_f32_16x16x32_bf16(af[i], bfv[j], acc[i][j], 0, 0, 0);
        __syncthreads();
        buf ^= 1;
    }

#pragma unroll
    for (int i = 0; i < 4; i++) {
        const int row = bm + wm + i * 16 + quad * 4;
#pragma unroll
        for (int j = 0; j < JF; j++) {
            const int col = bn + wn + j * 16 + l16;
            const float bv = bias[col];
#pragma unroll
            for (int r = 0; r < 4; r++) {
                float v = acc[i][j][r] + bv;
                if (EPI == 1) v += res[(size_t)(row + r) * N + col];
                store_out(&C[(size_t)(row + r) * N + col], v);
            }
        }
    }
}

// ---------------------------------------------------------------- GEMM 256x256 (deep pipe)
// A, Bt PACKED. 512 thr / 8 waves, NBUF=4 x 32KB A + 4 x 32KB B in ONE 128KB
// LDS pool, D=3, vmcnt(8) counted pipe (verified skeleton: s_barrier +
// sched_barrier(0), rule 18). EPI: 0 = bias, 2 = bias + exact GELU.
// PACKC: C written packed via LDS-staged coalesced copy (R17): the 256^2
// output tile is exactly 128KB = the LDS pool; each wave deposits its
// fragments into the packed image, then 512 threads copy 128 x 1KB blocks
// with contiguous 16B stores.
template <int EPI, bool PACKC, typename OutT>
__global__ __launch_bounds__(512, 2) void gemm_pipe256(
    const unsigned short* __restrict__ A, const unsigned short* __restrict__ Bt,
    const float* __restrict__ bp0, const float* __restrict__ bp1,
    const float* __restrict__ bp2, const float* __restrict__ bp3,
    OutT* __restrict__ C, int M, int N, int K) {
    constexpr int D = 3, NBUF = 4;
    __shared__ __align__(16) unsigned short lds[NBUF * 8192 * 2];   // 128 KB
#define AS17(b) (lds + (b) * 8192)
#define BS17(b) (lds + 32768 + (b) * 8192)
    const int tid = threadIdx.x;
    const int w = tid >> 6, lane = tid & 63;
    const int quad = lane >> 4, l16 = lane & 15;
    const int bm = blockIdx.x * 256, bn = blockIdx.y * 256;
    const int wm = (w & 1) * 128, wn = (w >> 1) * 64;   // 2m x 4n wave grid
    const int KT = K >> 5;

    f32x4_t acc[8][4];
#pragma unroll
    for (int i = 0; i < 8; i++)
#pragma unroll
        for (int j = 0; j < 4; j++) acc[i][j] = f32x4_t{0.f, 0.f, 0.f, 0.f};

    const unsigned short* Ab = A + (((size_t)(bm >> 4) * KT) << 9) + lane * 8;
    const unsigned short* Bb = Bt + (((size_t)(bn >> 4) * KT) << 9) + lane * 8;

    // 32 subtiles (16 A + 16 B) over 8 waves -> exactly 4 contiguous glds16/wave
    auto stage = [&](int kt, int bufi) {
        const int s0 = w * 2, s1 = s0 + 1;
        glds16(Ab + ((size_t)(s0 * KT + kt) << 9), AS17(bufi) + s0 * 512);
        glds16(Ab + ((size_t)(s1 * KT + kt) << 9), AS17(bufi) + s1 * 512);
        glds16(Bb + ((size_t)(s0 * KT + kt) << 9), BS17(bufi) + s0 * 512);
        glds16(Bb + ((size_t)(s1 * KT + kt) << 9), BS17(bufi) + s1 * 512);
    };
    auto compute = [&](int bufi) {
        bf16x8_t af[8], bfv[4];
#pragma unroll
        for (int i = 0; i < 8; i++)
            af[i] = as_bf(*(const u16x8*)(AS17(bufi) + ((wm >> 4) + i) * 512 + lane * 8));
#pragma unroll
        for (int j = 0; j < 4; j++)
            bfv[j] = as_bf(*(const u16x8*)(BS17(bufi) + ((wn >> 4) + j) * 512 + lane * 8));
#pragma unroll
        for (int i = 0; i < 8; i++)
#pragma unroll
            for (int j = 0; j < 4; j++)
                acc[i][j] = __builtin_amdgcn_mfma_f32_16x16x32_bf16(af[i], bfv[j], acc[i][j], 0, 0, 0);
    };

#pragma unroll
    for (int t = 0; t < D; ++t) stage(t, t);

    int buf = 0, sbuf = D;   // sbuf = (t+D) & 3
    for (int t = 0; t < KT - D; ++t) {
        wait_vm<8>();                        // tile t's 4 loads done (own wave)
        __builtin_amdgcn_s_barrier();        // everyone's tile-t loads done
        __builtin_amdgcn_sched_barrier(0);   // no ds_read hoisting above this
        stage(t + D, sbuf);
        sbuf = (sbuf + 1) & 3;
        compute(buf);
        buf = (buf + 1) & 3;
    }
    // tail: last D=3 tiles, decreasing in-flight counts
    wait_vm<8>(); __builtin_amdgcn_s_barrier(); __builtin_amdgcn_sched_barrier(0);
    compute(buf); buf = (buf + 1) & 3;
    wait_vm<4>(); __builtin_amdgcn_s_barrier(); __builtin_amdgcn_sched_barrier(0);
    compute(buf); buf = (buf + 1) & 3;
    wait_vm<0>(); __builtin_amdgcn_s_barrier(); __builtin_amdgcn_sched_barrier(0);
    compute(buf);

    if constexpr (PACKC) {
        // ---- R17 epilogue: packed C via LDS-staged coalesced copy
        __syncthreads();   // all waves done reading As/Bs
#pragma unroll
        for (int i = 0; i < 8; i++) {
            const int msub = (wm >> 4) + i;
#pragma unroll
            for (int j = 0; j < 4; j++) {
                const int nsub = (wn + j * 16) >> 5;
                const int col = bn + wn + j * 16 + l16;
                const int sel = col >> 10;
                const float* bp = (sel == 0) ? bp0 : (sel == 1) ? bp1 : (sel == 2) ? bp2 : bp3;
                const float bv = bp[col & 1023];
                unsigned short* dst = lds + (msub * 8 + nsub) * 512 +
                                      ((j & 1) * 2 + (l16 >> 3)) * 128 + (l16 & 7);
#pragma unroll
                for (int r = 0; r < 4; r++) {
                    float v = acc[i][j][r] + bv;
                    if (EPI == 2) v = 0.5f * v * (1.f + erff(v * 0.70710678118f));
                    dst[(quad * 4 + r) * 8] = f2b(v);
                }
            }
        }
        __syncthreads();
        // copy: 128 blocks x 1KB; thread -> (block tid>>2, quarter tid&3)
        const int blk = tid >> 2, quar = tid & 3;
        const int gm = (bm >> 4) + (blk >> 3);
        const int gn = (bn >> 5) + (blk & 7);
        unsigned short* gbase = (unsigned short*)C +
                                (((size_t)gm * (N >> 5) + gn) << 9) + quar * 128;
        const unsigned short* lbase = lds + blk * 512 + quar * 128;
#pragma unroll
        for (int c0 = 0; c0 < 16; c0++) {
            const int c = (c0 + (lane & 15)) & 15;   // rotate: spread LDS banks
            *(u16x8*)(gbase + c * 8) = *(const u16x8*)(lbase + c * 8);
        }
    } else {
#pragma unroll
        for (int i = 0; i < 8; i++) {
            const int row = bm + wm + i * 16 + quad * 4;
#pragma unroll
            for (int j = 0; j < 4; j++) {
                const int col = bn + wn + j * 16 + l16;
                const int sel = col >> 10;
                const float* bp = (sel == 0) ? bp0 : (sel == 1) ? bp1 : (sel == 2) ? bp2 : bp3;
                const float bv = bp[col & 1023];
#pragma unroll
                for (int r = 0; r < 4; r++) {
                    float v = acc[i][j][r] + bv;
                    if (EPI == 2) v = 0.5f * v * (1.f + erff(v * 0.70710678118f));
                    store_out(&C[(size_t)(row + r) * N + col], v);
                }
            }
        }
    }
#undef AS17
#undef BS17
}

// ---------------------------------------------------------------- Attention
// 128 Q-rows/block. Q,K: fused qkv rows (stride ld). Vt: packed panels.
// R19: 2-buffer __syncthreads staging (R5-verified structure) -> LDS 49.4KB
// -> 3 blocks/CU (was 66.5KB / 2 blocks). Output ctx PACKED (K-depth 1024).
#define LP 68   // Ps stride (write banks quad*8+l16/2 -> conflict-free)

__global__ __launch_bounds__(256, 3) void attn_kernel(
    const unsigned short* __restrict__ Q, const unsigned short* __restrict__ K,
    const unsigned short* __restrict__ Vt, unsigned short* __restrict__ O,
    int ld) {
    __shared__ __align__(16) unsigned short Ks[2][8 * 512];  // subtile jn*2+half
    __shared__ __align__(16) unsigned short Vs[2][8 * 512];  // subtile jd*2+half
    __shared__ __align__(16) unsigned short Ps[4][32 * LP];  // per-wave slab
    const int tid = threadIdx.x;
    const int w = tid >> 6, lane = tid & 63;
    const int quad = lane >> 4, l16 = lane & 15;
    const int hh = blockIdx.x >> 1, bb = blockIdx.x & 1;
    const int y = blockIdx.y;
    const int qb = (y >= 8) ? (y - 8) : (15 - y);   // pair qb with 15-qb per CU
    const int q0 = qb * 128;
    const int tmax = 2 * qb + 1;
    const size_t seqbase = (size_t)bb * 2048;
    const int hoff = hh * 64;
    const unsigned short* vtb = Vt + ((size_t)(bb * 16 + hh) << 17);
    const float cs = 0.18033688f;   // 0.125 * log2(e)

    // Q fragments: qf[i][half], rows q0+i*64+w*16+l16, cols half*32+quad*8
    bf16x8_t qf[2][2];
#pragma unroll
    for (int i = 0; i < 2; i++) {
        const unsigned short* qr = Q + (seqbase + q0 + i * 64 + w * 16 + l16) * ld + hoff;
        qf[i][0] = as_bf(*(const u16x8*)(qr + quad * 8));
        qf[i][1] = as_bf(*(const u16x8*)(qr + 32 + quad * 8));
    }

    f32x4_t o[2][4];
#pragma unroll
    for (int i = 0; i < 2; i++)
#pragma unroll
        for (int jd = 0; jd < 4; jd++) o[i][jd] = f32x4_t{0.f, 0.f, 0.f, 0.f};
    float ls[2][4] = {{0.f, 0.f, 0.f, 0.f}, {0.f, 0.f, 0.f, 0.f}};

    // stage tile t into buf: 16 subtile-issues, exactly 4 per wave.
    // K from qkv rows (segmented); V from packed panels (contiguous 1KB).
    auto stage = [&](int t, int buf) {
        for (int s = w; s < 16; s += 4) {
            if (s < 8) {
                const unsigned short* src =
                    K + (seqbase + t * 64 + (s >> 1) * 16 + l16) * ld + hoff + (s & 1) * 32 + quad * 8;
                glds16(src, &Ks[buf][s * 512]);
            } else {
                const int v = s - 8;
                const unsigned short* src =
                    vtb + ((size_t)((v >> 1) * 64 + t * 2 + (v & 1)) << 9) + lane * 8;
                glds16(src, &Vs[buf][v * 512]);
            }
        }
    };

    stage(0, 0);
    __syncthreads();

    int buf = 0;
    for (int t = 0; t <= tmax; ++t) {
        if (t < tmax) stage(t + 1, buf ^ 1);

        // ---- K/V fragments for this tile
        bf16x8_t kf[4][2], vf[4][2];
#pragma unroll
        for (int jn = 0; jn < 4; jn++) {
            kf[jn][0] = as_bf(*(const u16x8*)&Ks[buf][(jn * 2 + 0) * 512 + lane * 8]);
            kf[jn][1] = as_bf(*(const u16x8*)&Ks[buf][(jn * 2 + 1) * 512 + lane * 8]);
            vf[jn][0] = as_bf(*(const u16x8*)&Vs[buf][(jn * 2 + 0) * 512 + lane * 8]);
            vf[jn][1] = as_bf(*(const u16x8*)&Vs[buf][(jn * 2 + 1) * 512 + lane * 8]);
        }

        // ---- S = Q@K^T, exp2, deferred sum, P->LDS  (no cross-lane ops)
#pragma unroll
        for (int i = 0; i < 2; i++) {
            if (i == 0 && t > 2 * qb) continue;      // fully-masked subtile
            const bool diag = (t == 2 * qb + i);
#pragma unroll
            for (int jn = 0; jn < 4; jn++) {
                f32x4_t z = f32x4_t{0.f, 0.f, 0.f, 0.f};
                z = __builtin_amdgcn_mfma_f32_16x16x32_bf16(qf[i][0], kf[jn][0], z, 0, 0, 0);
                z = __builtin_amdgcn_mfma_f32_16x16x32_bf16(qf[i][1], kf[jn][1], z, 0, 0, 0);
#pragma unroll
                for (int r = 0; r < 4; r++) {
                    float p = exp2f(fminf(z[r] * cs, 60.f));
                    if (diag) {
                        const int col = t * 64 + jn * 16 + l16;
                        const int row = q0 + i * 64 + w * 16 + quad * 4 + r;
                        p = (col <= row) ? p : 0.f;
                    }
                    ls[i][r] += p;
                    Ps[w][(i * 16 + quad * 4 + r) * LP + jn * 16 + l16] = f2b(p);
                }
            }
        }

        // ---- O += P @ V  (wave-private P slab, no barrier needed)
#pragma unroll
        for (int i = 0; i < 2; i++) {
            if (i == 0 && t > 2 * qb) continue;
            const bf16x8_t pf0 = as_bf(*(const u16x8*)&Ps[w][(i * 16 + l16) * LP + quad * 8]);
            const bf16x8_t pf1 = as_bf(*(const u16x8*)&Ps[w][(i * 16 + l16) * LP + 32 + quad * 8]);
#pragma unroll
            for (int jd = 0; jd < 4; jd++) {
                o[i][jd] = __builtin_amdgcn_mfma_f32_16x16x32_bf16(pf0, vf[jd][0], o[i][jd], 0, 0, 0);
                o[i][jd] = __builtin_amdgcn_mfma_f32_16x16x32_bf16(pf1, vf[jd][1], o[i][jd], 0, 0, 0);
            }
        }
        __syncthreads();   // drains glds(t+1); all waves done with buf
        buf ^= 1;
    }

    // ---- epilogue: one cross-lane reduction per row, packed ctx store
#pragma unroll
    for (int i = 0; i < 2; i++)
#pragma unroll
        for (int r = 0; r < 4; r++) {
            float s = ls[i][r];
            s += __shfl_xor(s, 1);
            s += __shfl_xor(s, 2);
            s += __shfl_xor(s, 4);
            s += __shfl_xor(s, 8);
            const float inv = 1.f / s;
            const int row = (int)seqbase + q0 + i * 64 + w * 16 + quad * 4 + r;
#pragma unroll
            for (int jd = 0; jd < 4; jd++)
                O[pidx(row, hoff + jd * 16 + l16, 1024)] = f2b(o[i][jd][r] * inv);
        }
}

// ---------------------------------------------------------------- launch
extern "C" void kernel_launch(void* const* d_in, const int* in_sizes, int n_in,
                              void* d_out, int out_size, void* d_ws, size_t ws_size,
                              hipStream_t stream) {
    const float* x = (const float*)d_in[0];
    const float* ln1s = (const float*)d_in[1];
    const float* ln1b = (const float*)d_in[2];
    const float* ln2s = (const float*)d_in[3];
    const float* ln2b = (const float*)d_in[4];
    const float* wq = (const float*)d_in[5];
    const float* bq = (const float*)d_in[6];
    const float* wk = (const float*)d_in[7];
    const float* bk = (const float*)d_in[8];
    const float* wv = (const float*)d_in[9];
    const float* bv = (const float*)d_in[10];
    const float* wo = (const float*)d_in[11];
    const float* bo = (const float*)d_in[12];
    const float* w1 = (const float*)d_in[13];
    const float* b1 = (const float*)d_in[14];
    const float* w2 = (const float*)d_in[15];
    const float* b2 = (const float*)d_in[16];
    float* out = (float*)d_out;

    char* ws = (char*)d_ws;
    const size_t MB = 1u << 20;
    unsigned short* wqkvt = (unsigned short*)(ws + 0 * MB);
    unsigned short* wot   = (unsigned short*)(ws + 6 * MB);
    unsigned short* w1t   = (unsigned short*)(ws + 8 * MB);
    unsigned short* w2t   = (unsigned short*)(ws + 16 * MB);
    unsigned short* h     = (unsigned short*)(ws + 24 * MB);
    unsigned short* vt    = (unsigned short*)(ws + 24 * MB);
    unsigned short* qkv   = (unsigned short*)(ws + 32 * MB);
    unsigned short* ctx   = (unsigned short*)(ws + 56 * MB);
    unsigned short* h2    = (unsigned short*)(ws + 24 * MB);
    float*          x1    = (float*)(ws + 64 * MB);
    unsigned short* g     = (unsigned short*)(ws + 32 * MB);

    const dim3 blk(256);

    transpose_cast4<<<dim3(32, 32, 4), blk, 0, stream>>>(wq, wk, wv, wo, wqkvt, wot);
    transpose_cast<<<dim3(32, 128), blk, 0, stream>>>(w1, w1t, 1024, 4096);
    transpose_cast<<<dim3(128, 32), blk, 0, stream>>>(w2, w2t, 4096, 1024);

    ln_kernel<<<4096, blk, 0, stream>>>(x, ln1s, ln1b, h);
    // qkv GEMM: 256x256 deep pipe (A,B packed; C row-major for attn)
    gemm_pipe256<0, false, unsigned short><<<dim3(16, 12), dim3(512), 0, stream>>>(
        h, wqkvt, bq, bk, bv, bv, qkv, 4096, 3072, 1024);
    vtrans_kernel<<<dim3(64, 32, 2), blk, 0, stream>>>(qkv + 2048, vt);
    attn_kernel<<<dim3(32, 16), blk, 0, stream>>>(qkv, qkv + 1024, vt, ctx, 3072);
    // wo GEMM: BN=64 2-barrier (A=ctx packed, B packed), res=x, out=x1 fp32
    gemm_kernel<64, 1, float><<<dim3(32, 16), blk, 0, stream>>>(
        ctx, wot, bo, x, x1, 4096, 1024, 1024);
    ln_kernel<<<4096, blk, 0, stream>>>(x1, ln2s, ln2b, h2);
    // w1 GEMM: 256x256 deep pipe + GELU (A=h2 packed, B packed, C=g PACKED
    // via LDS-staged coalesced store - R17)
    gemm_pipe256<2, true, unsigned short><<<dim3(16, 16), dim3(512), 0, stream>>>(
        h2, w1t, b1, b1 + 1024, b1 + 2048, b1 + 3072, g, 4096, 4096, 1024);
    // w2 GEMM: BN=64 2-barrier (A=g packed, B packed), res=x1, out
    gemm_kernel<64, 1, float><<<dim3(32, 16), blk, 0, stream>>>(
        g, w2t, b2, x1, out, 4096, 1024, 4096);
}

// Round 15
// 402.106 us; speedup vs baseline: 1.0454x; 1.0454x over previous
//
#include <hip/hip_runtime.h>

// TransformerBlock on MI355X (gfx950). fp32 I/O, bf16 MFMA compute.
// B=2 S=2048 D=1024 H=16 Dh=64 HIDDEN=4096, causal, exact GELU.
//
// Round 20: R19 null (420us) - attn LDS cut was useless because the GRID
// (512 blocks) caps occupancy at 2 blocks/CU; LDS was never binding.
// attn counters: MfmaUtil 8.4 / VALUBusy 41.5 / HBM 3% -> VALU-bound with
// unhidden chains at 8 waves/CU. Fix: 64-row Q blocks -> grid (32,32) =
// 1024 blocks = 4/CU launched, 3 resident by LDS (41.5KB), 12 waves/CU;
// same total work, 2x latency hiding, smaller qb-tail. Pairing y<->31-y.
// GEMM tier unchanged from the 419us champion (packed operands + R17
// LDS-staged packed C; w2 now 80.6us, all GEMMs <83us).
// Packed element (m,k), K-depth: addr = ((m>>4)*(K>>5)+(k>>5))*512
//                                     + ((k&31)>>3)*128 + (m&15)*8 + (k&7).
// Workspace (80 MB):
//   [ 0, 6M) wqkv^T  [ 6, 8M) wo^T  [ 8,16M) w1^T  [16,24M) w2^T
//   [24,32M) h -> vt (V^T) -> h2    [32,56M) qkv -> g(32MB spans [32,64M))
//   [56,64M) ctx     [64,80M) x1 (fp32)

typedef __bf16 bf16x8_t __attribute__((ext_vector_type(8)));
typedef float f32x4_t __attribute__((ext_vector_type(4)));
typedef unsigned short u16x8 __attribute__((ext_vector_type(8)));

__device__ __forceinline__ unsigned short f2b(float f) {
    unsigned int u = __builtin_bit_cast(unsigned int, f);
    u += 0x7fffu + ((u >> 16) & 1u);   // round-to-nearest-even
    return (unsigned short)(u >> 16);
}
__device__ __forceinline__ bf16x8_t as_bf(u16x8 v) {
    return __builtin_bit_cast(bf16x8_t, v);
}
__device__ __forceinline__ void store_out(float* p, float v) { *p = v; }
__device__ __forceinline__ void store_out(unsigned short* p, float v) { *p = f2b(v); }

// packed-subtile index: element (m,k) of an [M][K] bf16 operand
__device__ __forceinline__ size_t pidx(int m, int k, int K) {
    return (((size_t)((m >> 4) * (K >> 5) + (k >> 5))) << 9) +
           (((k & 31) >> 3) << 7) + ((m & 15) << 3) + (k & 7);
}

// async global->LDS, 16B per lane; lds dest must be wave-uniform base
__device__ __forceinline__ void glds16(const unsigned short* g, unsigned short* l) {
    __builtin_amdgcn_global_load_lds(
        (const __attribute__((address_space(1))) unsigned int*)g,
        (__attribute__((address_space(3))) unsigned int*)l, 16, 0, 0);
}

template <int N>
__device__ __forceinline__ void wait_vm() {
    asm volatile("s_waitcnt vmcnt(%0)" ::"i"(N) : "memory");
}

// -------------------------------------------------- transpose + cast weights
// src [K][N] fp32 -> packed B (element (n,k) = src[k][n]), K-depth = K
__global__ __launch_bounds__(256) void transpose_cast(
    const float* __restrict__ src, unsigned short* __restrict__ dst,
    int K, int N) {
    __shared__ float tile[32][33];
    const int k0 = blockIdx.x * 32, n0 = blockIdx.y * 32;
    const int c = threadIdx.x & 31, r8 = threadIdx.x >> 5;
#pragma unroll
    for (int i = 0; i < 4; i++) {
        const int r = r8 + i * 8;
        tile[r][c] = src[(size_t)(k0 + r) * N + n0 + c];
    }
    __syncthreads();
#pragma unroll
    for (int i = 0; i < 4; i++) {
        const int rr = r8 + i * 8;
        dst[pidx(n0 + rr, k0 + c, K)] = f2b(tile[c][rr]);
    }
}

// four 1024x1024 weight transposes batched (wq,wk,wv -> wqkvt; wo -> wot), packed
__global__ __launch_bounds__(256) void transpose_cast4(
    const float* __restrict__ s0, const float* __restrict__ s1,
    const float* __restrict__ s2, const float* __restrict__ s3,
    unsigned short* __restrict__ wqkvt, unsigned short* __restrict__ wot) {
    __shared__ float tile[32][33];
    const int z = blockIdx.z;
    const float* src = (z == 0) ? s0 : (z == 1) ? s1 : (z == 2) ? s2 : s3;
    unsigned short* dst = (z < 3) ? wqkvt + ((size_t)z << 20) : wot;
    const int k0 = blockIdx.x * 32, n0 = blockIdx.y * 32;
    const int c = threadIdx.x & 31, r8 = threadIdx.x >> 5;
#pragma unroll
    for (int i = 0; i < 4; i++) {
        const int r = r8 + i * 8;
        tile[r][c] = src[(size_t)(k0 + r) * 1024 + n0 + c];
    }
    __syncthreads();
#pragma unroll
    for (int i = 0; i < 4; i++) {
        const int rr = r8 + i * 8;
        dst[pidx(n0 + rr, k0 + c, 1024)] = f2b(tile[c][rr]);
    }
}

// -------------------------------------------------- V -> V^T packed per (b,head)
// src: qkv V columns (rows of 3072-stride). dst: panel (b*16+h) of [64][2048],
// packed subtiles (K-depth 2048). panel stride 64*2048 = 1<<17.
__global__ __launch_bounds__(256) void vtrans_kernel(
    const unsigned short* __restrict__ src, unsigned short* __restrict__ dst) {
    __shared__ unsigned short tile[32][34];
    const int s0 = blockIdx.x * 32, hd0 = blockIdx.y * 32, b = blockIdx.z;
    const int c = threadIdx.x & 31, r8 = threadIdx.x >> 5;
#pragma unroll
    for (int i = 0; i < 4; i++) {
        const int r = r8 + i * 8;
        tile[r][c] = src[(size_t)(b * 2048 + s0 + r) * 3072 + hd0 + c];
    }
    __syncthreads();
#pragma unroll
    for (int i = 0; i < 4; i++) {
        const int rr = r8 + i * 8;
        const int g = b * 1024 + hd0 + rr;        // global hd row
        const int panel = g >> 6, local = g & 63;
        dst[((size_t)panel << 17) + pidx(local, s0 + c, 2048)] = tile[c][rr];
    }
}

// ---------------------------------------------------------------- LayerNorm
// output PACKED (K-depth 1024) - consumed only by GEMM A-staging.
__global__ __launch_bounds__(256) void ln_kernel(
    const float* __restrict__ X,
    const float* __restrict__ scale,
    const float* __restrict__ shift,
    unsigned short* __restrict__ Hout) {
    const int tok = blockIdx.x;
    const int tid = threadIdx.x;
    const size_t base = (size_t)tok * 1024 + tid * 4;
    float4 xv = *(const float4*)(X + base);
    float f[4] = {xv.x, xv.y, xv.z, xv.w};
    float s = 0.f, s2 = 0.f;
#pragma unroll
    for (int i = 0; i < 4; i++) { s += f[i]; s2 += f[i] * f[i]; }
#pragma unroll
    for (int off = 32; off >= 1; off >>= 1) {
        s += __shfl_down(s, off);
        s2 += __shfl_down(s2, off);
    }
    __shared__ float red[8];
    const int wv = tid >> 6;
    if ((tid & 63) == 0) { red[wv] = s; red[4 + wv] = s2; }
    __syncthreads();
    s = red[0] + red[1] + red[2] + red[3];
    s2 = red[4] + red[5] + red[6] + red[7];
    const float mean = s * (1.f / 1024.f);
    const float var = s2 * (1.f / 1024.f) - mean * mean;
    const float rstd = rsqrtf(var + 1e-5f);
    const float4 sc = *(const float4*)(scale + tid * 4);
    const float4 sh = *(const float4*)(shift + tid * 4);
    unsigned short ov[4];
    ov[0] = f2b((f[0] - mean) * rstd * sc.x + sh.x);
    ov[1] = f2b((f[1] - mean) * rstd * sc.y + sh.y);
    ov[2] = f2b((f[2] - mean) * rstd * sc.z + sh.z);
    ov[3] = f2b((f[3] - mean) * rstd * sc.w + sh.w);
    *(unsigned long long*)(Hout + pidx(tok, tid * 4, 1024)) = *(unsigned long long*)ov;
}

// ---------------------------------------------------------------- GEMM (2-barrier)
// A, Bt PACKED. EPI: 1 = bias + residual (res row-major fp32).
template <int BN, int EPI, typename OutT>
__global__ __launch_bounds__(256) void gemm_kernel(
    const unsigned short* __restrict__ A, const unsigned short* __restrict__ Bt,
    const float* __restrict__ bias, const float* __restrict__ res,
    OutT* __restrict__ C, int M, int N, int K) {
    constexpr int BSUB = BN / 16;
    constexpr int JF = BN / 32;
    __shared__ __align__(16) unsigned short As[2][8 * 512];
    __shared__ __align__(16) unsigned short Bs[2][BSUB * 512];
    const int tid = threadIdx.x;
    const int w = tid >> 6, lane = tid & 63;
    const int quad = lane >> 4, l16 = lane & 15;
    const int bm = blockIdx.x * 128, bn = blockIdx.y * BN;
    const int wm = (w & 1) * 64, wn = (w >> 1) * (BN / 2);
    const int KT = K >> 5;

    f32x4_t acc[4][JF];
#pragma unroll
    for (int i = 0; i < 4; i++)
#pragma unroll
        for (int j = 0; j < JF; j++) acc[i][j] = f32x4_t{0.f, 0.f, 0.f, 0.f};

    // packed: subtile s at k-tile kt is one contiguous 1KB block
    const unsigned short* Ab = A + (((size_t)(bm >> 4) * KT) << 9) + lane * 8;
    const unsigned short* Bb = Bt + (((size_t)(bn >> 4) * KT) << 9) + lane * 8;

    {
        for (int s = w; s < 8; s += 4)
            glds16(Ab + ((size_t)(s * KT) << 9), &As[0][s * 512]);
        for (int s = w; s < BSUB; s += 4)
            glds16(Bb + ((size_t)(s * KT) << 9), &Bs[0][s * 512]);
    }
    __syncthreads();

    int buf = 0;
    for (int kt = 0; kt < KT; ++kt) {
        if (kt + 1 < KT) {
            for (int s = w; s < 8; s += 4)
                glds16(Ab + ((size_t)(s * KT + kt + 1) << 9), &As[buf ^ 1][s * 512]);
            for (int s = w; s < BSUB; s += 4)
                glds16(Bb + ((size_t)(s * KT + kt + 1) << 9), &Bs[buf ^ 1][s * 512]);
        }
        bf16x8_t af[4], bfv[JF];
#pragma unroll
        for (int i = 0; i < 4; i++)
            af[i] = as_bf(*(const u16x8*)&As[buf][((wm >> 4) + i) * 512 + lane * 8]);
#pragma unroll
        for (int j = 0; j < JF; j++)
            bfv[j] = as_bf(*(const u16x8*)&Bs[buf][((wn >> 4) + j) * 512 + lane * 8]);
#pragma unroll
        for (int i = 0; i < 4; i++)
#pragma unroll
            for (int j = 0; j < JF; j++)
                acc[i][j] = __builtin_amdgcn_mfma_f32_16x16x32_bf16(af[i], bfv[j], acc[i][j], 0, 0, 0);
        __syncthreads();
        buf ^= 1;
    }

#pragma unroll
    for (int i = 0; i < 4; i++) {
        const int row = bm + wm + i * 16 + quad * 4;
#pragma unroll
        for (int j = 0; j < JF; j++) {
            const int col = bn + wn + j * 16 + l16;
            const float bv = bias[col];
#pragma unroll
            for (int r = 0; r < 4; r++) {
                float v = acc[i][j][r] + bv;
                if (EPI == 1) v += res[(size_t)(row + r) * N + col];
                store_out(&C[(size_t)(row + r) * N + col], v);
            }
        }
    }
}

// ---------------------------------------------------------------- GEMM 256x256 (deep pipe)
// A, Bt PACKED. 512 thr / 8 waves, NBUF=4 x 32KB A + 4 x 32KB B in ONE 128KB
// LDS pool, D=3, vmcnt(8) counted pipe (verified skeleton: s_barrier +
// sched_barrier(0), rule 18). EPI: 0 = bias, 2 = bias + exact GELU.
// PACKC: C written packed via LDS-staged coalesced copy (R17).
template <int EPI, bool PACKC, typename OutT>
__global__ __launch_bounds__(512, 2) void gemm_pipe256(
    const unsigned short* __restrict__ A, const unsigned short* __restrict__ Bt,
    const float* __restrict__ bp0, const float* __restrict__ bp1,
    const float* __restrict__ bp2, const float* __restrict__ bp3,
    OutT* __restrict__ C, int M, int N, int K) {
    constexpr int D = 3, NBUF = 4;
    __shared__ __align__(16) unsigned short lds[NBUF * 8192 * 2];   // 128 KB
#define AS17(b) (lds + (b) * 8192)
#define BS17(b) (lds + 32768 + (b) * 8192)
    const int tid = threadIdx.x;
    const int w = tid >> 6, lane = tid & 63;
    const int quad = lane >> 4, l16 = lane & 15;
    const int bm = blockIdx.x * 256, bn = blockIdx.y * 256;
    const int wm = (w & 1) * 128, wn = (w >> 1) * 64;   // 2m x 4n wave grid
    const int KT = K >> 5;

    f32x4_t acc[8][4];
#pragma unroll
    for (int i = 0; i < 8; i++)
#pragma unroll
        for (int j = 0; j < 4; j++) acc[i][j] = f32x4_t{0.f, 0.f, 0.f, 0.f};

    const unsigned short* Ab = A + (((size_t)(bm >> 4) * KT) << 9) + lane * 8;
    const unsigned short* Bb = Bt + (((size_t)(bn >> 4) * KT) << 9) + lane * 8;

    // 32 subtiles (16 A + 16 B) over 8 waves -> exactly 4 contiguous glds16/wave
    auto stage = [&](int kt, int bufi) {
        const int s0 = w * 2, s1 = s0 + 1;
        glds16(Ab + ((size_t)(s0 * KT + kt) << 9), AS17(bufi) + s0 * 512);
        glds16(Ab + ((size_t)(s1 * KT + kt) << 9), AS17(bufi) + s1 * 512);
        glds16(Bb + ((size_t)(s0 * KT + kt) << 9), BS17(bufi) + s0 * 512);
        glds16(Bb + ((size_t)(s1 * KT + kt) << 9), BS17(bufi) + s1 * 512);
    };
    auto compute = [&](int bufi) {
        bf16x8_t af[8], bfv[4];
#pragma unroll
        for (int i = 0; i < 8; i++)
            af[i] = as_bf(*(const u16x8*)(AS17(bufi) + ((wm >> 4) + i) * 512 + lane * 8));
#pragma unroll
        for (int j = 0; j < 4; j++)
            bfv[j] = as_bf(*(const u16x8*)(BS17(bufi) + ((wn >> 4) + j) * 512 + lane * 8));
#pragma unroll
        for (int i = 0; i < 8; i++)
#pragma unroll
            for (int j = 0; j < 4; j++)
                acc[i][j] = __builtin_amdgcn_mfma_f32_16x16x32_bf16(af[i], bfv[j], acc[i][j], 0, 0, 0);
    };

#pragma unroll
    for (int t = 0; t < D; ++t) stage(t, t);

    int buf = 0, sbuf = D;   // sbuf = (t+D) & 3
    for (int t = 0; t < KT - D; ++t) {
        wait_vm<8>();                        // tile t's 4 loads done (own wave)
        __builtin_amdgcn_s_barrier();        // everyone's tile-t loads done
        __builtin_amdgcn_sched_barrier(0);   // no ds_read hoisting above this
        stage(t + D, sbuf);
        sbuf = (sbuf + 1) & 3;
        compute(buf);
        buf = (buf + 1) & 3;
    }
    // tail: last D=3 tiles, decreasing in-flight counts
    wait_vm<8>(); __builtin_amdgcn_s_barrier(); __builtin_amdgcn_sched_barrier(0);
    compute(buf); buf = (buf + 1) & 3;
    wait_vm<4>(); __builtin_amdgcn_s_barrier(); __builtin_amdgcn_sched_barrier(0);
    compute(buf); buf = (buf + 1) & 3;
    wait_vm<0>(); __builtin_amdgcn_s_barrier(); __builtin_amdgcn_sched_barrier(0);
    compute(buf);

    if constexpr (PACKC) {
        // ---- R17 epilogue: packed C via LDS-staged coalesced copy
        __syncthreads();   // all waves done reading As/Bs
#pragma unroll
        for (int i = 0; i < 8; i++) {
            const int msub = (wm >> 4) + i;
#pragma unroll
            for (int j = 0; j < 4; j++) {
                const int nsub = (wn + j * 16) >> 5;
                const int col = bn + wn + j * 16 + l16;
                const int sel = col >> 10;
                const float* bp = (sel == 0) ? bp0 : (sel == 1) ? bp1 : (sel == 2) ? bp2 : bp3;
                const float bv = bp[col & 1023];
                unsigned short* dst = lds + (msub * 8 + nsub) * 512 +
                                      ((j & 1) * 2 + (l16 >> 3)) * 128 + (l16 & 7);
#pragma unroll
                for (int r = 0; r < 4; r++) {
                    float v = acc[i][j][r] + bv;
                    if (EPI == 2) v = 0.5f * v * (1.f + erff(v * 0.70710678118f));
                    dst[(quad * 4 + r) * 8] = f2b(v);
                }
            }
        }
        __syncthreads();
        // copy: 128 blocks x 1KB; thread -> (block tid>>2, quarter tid&3)
        const int blk = tid >> 2, quar = tid & 3;
        const int gm = (bm >> 4) + (blk >> 3);
        const int gn = (bn >> 5) + (blk & 7);
        unsigned short* gbase = (unsigned short*)C +
                                (((size_t)gm * (N >> 5) + gn) << 9) + quar * 128;
        const unsigned short* lbase = lds + blk * 512 + quar * 128;
#pragma unroll
        for (int c0 = 0; c0 < 16; c0++) {
            const int c = (c0 + (lane & 15)) & 15;   // rotate: spread LDS banks
            *(u16x8*)(gbase + c * 8) = *(const u16x8*)(lbase + c * 8);
        }
    } else {
#pragma unroll
        for (int i = 0; i < 8; i++) {
            const int row = bm + wm + i * 16 + quad * 4;
#pragma unroll
            for (int j = 0; j < 4; j++) {
                const int col = bn + wn + j * 16 + l16;
                const int sel = col >> 10;
                const float* bp = (sel == 0) ? bp0 : (sel == 1) ? bp1 : (sel == 2) ? bp2 : bp3;
                const float bv = bp[col & 1023];
#pragma unroll
                for (int r = 0; r < 4; r++) {
                    float v = acc[i][j][r] + bv;
                    if (EPI == 2) v = 0.5f * v * (1.f + erff(v * 0.70710678118f));
                    store_out(&C[(size_t)(row + r) * N + col], v);
                }
            }
        }
    }
#undef AS17
#undef BS17
}

// ---------------------------------------------------------------- Attention
// R20: 64 Q-rows/block (1 subtile/wave), grid (32, 32) = 1024 blocks ->
// 3 blocks/CU resident (LDS 41.5KB), 12 waves/CU. 2-buffer __syncthreads
// staging; K from qkv rows, V from packed panels; ctx PACKED out.
#define LP 68   // Ps stride (write banks 2-way max -> conflict-free)

__global__ __launch_bounds__(256, 3) void attn_kernel(
    const unsigned short* __restrict__ Q, const unsigned short* __restrict__ K,
    const unsigned short* __restrict__ Vt, unsigned short* __restrict__ O,
    int ld) {
    __shared__ __align__(16) unsigned short Ks[2][8 * 512];  // subtile jn*2+half
    __shared__ __align__(16) unsigned short Vs[2][8 * 512];  // subtile jd*2+half
    __shared__ __align__(16) unsigned short Ps[4][16 * LP];  // per-wave slab
    const int tid = threadIdx.x;
    const int w = tid >> 6, lane = tid & 63;
    const int quad = lane >> 4, l16 = lane & 15;
    const int hh = blockIdx.x >> 1, bb = blockIdx.x & 1;
    const int y = blockIdx.y;
    const int qb = (y >= 16) ? (y - 16) : (31 - y);   // pair qb with 31-qb
    const int q0 = qb * 64;
    const int tmax = qb;                              // diag tile = qb
    const size_t seqbase = (size_t)bb * 2048;
    const int hoff = hh * 64;
    const unsigned short* vtb = Vt + ((size_t)(bb * 16 + hh) << 17);
    const float cs = 0.18033688f;   // 0.125 * log2(e)

    // Q fragment: rows q0+w*16+l16, cols half*32+quad*8
    bf16x8_t qf[2];
    {
        const unsigned short* qr = Q + (seqbase + q0 + w * 16 + l16) * ld + hoff;
        qf[0] = as_bf(*(const u16x8*)(qr + quad * 8));
        qf[1] = as_bf(*(const u16x8*)(qr + 32 + quad * 8));
    }

    f32x4_t o[4];
#pragma unroll
    for (int jd = 0; jd < 4; jd++) o[jd] = f32x4_t{0.f, 0.f, 0.f, 0.f};
    float ls[4] = {0.f, 0.f, 0.f, 0.f};

    // stage tile t into buf: 16 subtile-issues, exactly 4 per wave.
    auto stage = [&](int t, int buf) {
        for (int s = w; s < 16; s += 4) {
            if (s < 8) {
                const unsigned short* src =
                    K + (seqbase + t * 64 + (s >> 1) * 16 + l16) * ld + hoff + (s & 1) * 32 + quad * 8;
                glds16(src, &Ks[buf][s * 512]);
            } else {
                const int v = s - 8;
                const unsigned short* src =
                    vtb + ((size_t)((v >> 1) * 64 + t * 2 + (v & 1)) << 9) + lane * 8;
                glds16(src, &Vs[buf][v * 512]);
            }
        }
    };

    stage(0, 0);
    __syncthreads();

    int buf = 0;
    for (int t = 0; t <= tmax; ++t) {
        if (t < tmax) stage(t + 1, buf ^ 1);

        // ---- K/V fragments for this tile
        bf16x8_t kf[4][2], vf[4][2];
#pragma unroll
        for (int jn = 0; jn < 4; jn++) {
            kf[jn][0] = as_bf(*(const u16x8*)&Ks[buf][(jn * 2 + 0) * 512 + lane * 8]);
            kf[jn][1] = as_bf(*(const u16x8*)&Ks[buf][(jn * 2 + 1) * 512 + lane * 8]);
            vf[jn][0] = as_bf(*(const u16x8*)&Vs[buf][(jn * 2 + 0) * 512 + lane * 8]);
            vf[jn][1] = as_bf(*(const u16x8*)&Vs[buf][(jn * 2 + 1) * 512 + lane * 8]);
        }

        // ---- S = Q@K^T, exp2, deferred sum, P->LDS  (no cross-lane ops)
        {
            const bool diag = (t == tmax);
#pragma unroll
            for (int jn = 0; jn < 4; jn++) {
                f32x4_t z = f32x4_t{0.f, 0.f, 0.f, 0.f};
                z = __builtin_amdgcn_mfma_f32_16x16x32_bf16(qf[0], kf[jn][0], z, 0, 0, 0);
                z = __builtin_amdgcn_mfma_f32_16x16x32_bf16(qf[1], kf[jn][1], z, 0, 0, 0);
#pragma unroll
                for (int r = 0; r < 4; r++) {
                    float p = exp2f(fminf(z[r] * cs, 60.f));
                    if (diag) {
                        const int col = t * 64 + jn * 16 + l16;
                        const int row = q0 + w * 16 + quad * 4 + r;
                        p = (col <= row) ? p : 0.f;
                    }
                    ls[r] += p;
                    Ps[w][(quad * 4 + r) * LP + jn * 16 + l16] = f2b(p);
                }
            }
        }

        // ---- O += P @ V  (wave-private P slab, no barrier needed)
        {
            const bf16x8_t pf0 = as_bf(*(const u16x8*)&Ps[w][l16 * LP + quad * 8]);
            const bf16x8_t pf1 = as_bf(*(const u16x8*)&Ps[w][l16 * LP + 32 + quad * 8]);
#pragma unroll
            for (int jd = 0; jd < 4; jd++) {
                o[jd] = __builtin_amdgcn_mfma_f32_16x16x32_bf16(pf0, vf[jd][0], o[jd], 0, 0, 0);
                o[jd] = __builtin_amdgcn_mfma_f32_16x16x32_bf16(pf1, vf[jd][1], o[jd], 0, 0, 0);
            }
        }
        __syncthreads();   // drains glds(t+1); all waves done with buf
        buf ^= 1;
    }

    // ---- epilogue: one cross-lane reduction per row, packed ctx store
#pragma unroll
    for (int r = 0; r < 4; r++) {
        float s = ls[r];
        s += __shfl_xor(s, 1);
        s += __shfl_xor(s, 2);
        s += __shfl_xor(s, 4);
        s += __shfl_xor(s, 8);
        const float inv = 1.f / s;
        const int row = (int)seqbase + q0 + w * 16 + quad * 4 + r;
#pragma unroll
        for (int jd = 0; jd < 4; jd++)
            O[pidx(row, hoff + jd * 16 + l16, 1024)] = f2b(o[jd][r] * inv);
    }
}

// ---------------------------------------------------------------- launch
extern "C" void kernel_launch(void* const* d_in, const int* in_sizes, int n_in,
                              void* d_out, int out_size, void* d_ws, size_t ws_size,
                              hipStream_t stream) {
    const float* x = (const float*)d_in[0];
    const float* ln1s = (const float*)d_in[1];
    const float* ln1b = (const float*)d_in[2];
    const float* ln2s = (const float*)d_in[3];
    const float* ln2b = (const float*)d_in[4];
    const float* wq = (const float*)d_in[5];
    const float* bq = (const float*)d_in[6];
    const float* wk = (const float*)d_in[7];
    const float* bk = (const float*)d_in[8];
    const float* wv = (const float*)d_in[9];
    const float* bv = (const float*)d_in[10];
    const float* wo = (const float*)d_in[11];
    const float* bo = (const float*)d_in[12];
    const float* w1 = (const float*)d_in[13];
    const float* b1 = (const float*)d_in[14];
    const float* w2 = (const float*)d_in[15];
    const float* b2 = (const float*)d_in[16];
    float* out = (float*)d_out;

    char* ws = (char*)d_ws;
    const size_t MB = 1u << 20;
    unsigned short* wqkvt = (unsigned short*)(ws + 0 * MB);
    unsigned short* wot   = (unsigned short*)(ws + 6 * MB);
    unsigned short* w1t   = (unsigned short*)(ws + 8 * MB);
    unsigned short* w2t   = (unsigned short*)(ws + 16 * MB);
    unsigned short* h     = (unsigned short*)(ws + 24 * MB);
    unsigned short* vt    = (unsigned short*)(ws + 24 * MB);
    unsigned short* qkv   = (unsigned short*)(ws + 32 * MB);
    unsigned short* ctx   = (unsigned short*)(ws + 56 * MB);
    unsigned short* h2    = (unsigned short*)(ws + 24 * MB);
    float*          x1    = (float*)(ws + 64 * MB);
    unsigned short* g     = (unsigned short*)(ws + 32 * MB);

    const dim3 blk(256);

    transpose_cast4<<<dim3(32, 32, 4), blk, 0, stream>>>(wq, wk, wv, wo, wqkvt, wot);
    transpose_cast<<<dim3(32, 128), blk, 0, stream>>>(w1, w1t, 1024, 4096);
    transpose_cast<<<dim3(128, 32), blk, 0, stream>>>(w2, w2t, 4096, 1024);

    ln_kernel<<<4096, blk, 0, stream>>>(x, ln1s, ln1b, h);
    // qkv GEMM: 256x256 deep pipe (A,B packed; C row-major for attn)
    gemm_pipe256<0, false, unsigned short><<<dim3(16, 12), dim3(512), 0, stream>>>(
        h, wqkvt, bq, bk, bv, bv, qkv, 4096, 3072, 1024);
    vtrans_kernel<<<dim3(64, 32, 2), blk, 0, stream>>>(qkv + 2048, vt);
    // attn: 64-row blocks, grid (32,32) = 1024 blocks (R20)
    attn_kernel<<<dim3(32, 32), blk, 0, stream>>>(qkv, qkv + 1024, vt, ctx, 3072);
    // wo GEMM: BN=64 2-barrier (A=ctx packed, B packed), res=x, out=x1 fp32
    gemm_kernel<64, 1, float><<<dim3(32, 16), blk, 0, stream>>>(
        ctx, wot, bo, x, x1, 4096, 1024, 1024);
    ln_kernel<<<4096, blk, 0, stream>>>(x1, ln2s, ln2b, h2);
    // w1 GEMM: 256x256 deep pipe + GELU (A=h2 packed, B packed, C=g PACKED
    // via LDS-staged coalesced store - R17)
    gemm_pipe256<2, true, unsigned short><<<dim3(16, 16), dim3(512), 0, stream>>>(
        h2, w1t, b1, b1 + 1024, b1 + 2048, b1 + 3072, g, 4096, 4096, 1024);
    // w2 GEMM: BN=64 2-barrier (A=g packed, B packed), res=x1, out
    gemm_kernel<64, 1, float><<<dim3(32, 16), blk, 0, stream>>>(
        g, w2t, b2, x1, out, 4096, 1024, 4096);
}

// Round 16
// 395.467 us; speedup vs baseline: 1.0629x; 1.0168x over previous
//
#include <hip/hip_runtime.h>

// TransformerBlock on MI355X (gfx950). fp32 I/O, bf16 MFMA compute.
// B=2 S=2048 D=1024 H=16 Dh=64 HIDDEN=4096, causal, exact GELU.
//
// Round 21: R20 = 402us champion (64-row attn blocks -> attn <79us). Top-5
// is now w2 x5 at 79us: MfmaUtil 16.5 / VALU 19 / HBM 12 / Occ 20 ->
// latency-bound on the 2-barrier loop's per-step vmcnt(0) drain. Packing
// removed the request-rate wall that masked R9's null, so the counted-vmcnt
// pipe should now pay: gemm_pipe64 (R9-verified skeleton: NBUF=5, D=4,
// 3 glds16/wave/step, wait_vm<9>, tail 9/6/3/0, s_barrier+sched_barrier(0))
// with packed contiguous 1KB subtile loads, for wo + w2. LDS 60KB ->
// still 2 blocks/CU. Everything else identical to R20.
// Packed element (m,k), K-depth: addr = ((m>>4)*(K>>5)+(k>>5))*512
//                                     + ((k&31)>>3)*128 + (m&15)*8 + (k&7).
// Workspace (80 MB):
//   [ 0, 6M) wqkv^T  [ 6, 8M) wo^T  [ 8,16M) w1^T  [16,24M) w2^T
//   [24,32M) h -> vt (V^T) -> h2    [32,56M) qkv -> g(32MB spans [32,64M))
//   [56,64M) ctx     [64,80M) x1 (fp32)

typedef __bf16 bf16x8_t __attribute__((ext_vector_type(8)));
typedef float f32x4_t __attribute__((ext_vector_type(4)));
typedef unsigned short u16x8 __attribute__((ext_vector_type(8)));

__device__ __forceinline__ unsigned short f2b(float f) {
    unsigned int u = __builtin_bit_cast(unsigned int, f);
    u += 0x7fffu + ((u >> 16) & 1u);   // round-to-nearest-even
    return (unsigned short)(u >> 16);
}
__device__ __forceinline__ bf16x8_t as_bf(u16x8 v) {
    return __builtin_bit_cast(bf16x8_t, v);
}
__device__ __forceinline__ void store_out(float* p, float v) { *p = v; }
__device__ __forceinline__ void store_out(unsigned short* p, float v) { *p = f2b(v); }

// packed-subtile index: element (m,k) of an [M][K] bf16 operand
__device__ __forceinline__ size_t pidx(int m, int k, int K) {
    return (((size_t)((m >> 4) * (K >> 5) + (k >> 5))) << 9) +
           (((k & 31) >> 3) << 7) + ((m & 15) << 3) + (k & 7);
}

// async global->LDS, 16B per lane; lds dest must be wave-uniform base
__device__ __forceinline__ void glds16(const unsigned short* g, unsigned short* l) {
    __builtin_amdgcn_global_load_lds(
        (const __attribute__((address_space(1))) unsigned int*)g,
        (__attribute__((address_space(3))) unsigned int*)l, 16, 0, 0);
}

template <int N>
__device__ __forceinline__ void wait_vm() {
    asm volatile("s_waitcnt vmcnt(%0)" ::"i"(N) : "memory");
}

// -------------------------------------------------- transpose + cast weights
// src [K][N] fp32 -> packed B (element (n,k) = src[k][n]), K-depth = K
__global__ __launch_bounds__(256) void transpose_cast(
    const float* __restrict__ src, unsigned short* __restrict__ dst,
    int K, int N) {
    __shared__ float tile[32][33];
    const int k0 = blockIdx.x * 32, n0 = blockIdx.y * 32;
    const int c = threadIdx.x & 31, r8 = threadIdx.x >> 5;
#pragma unroll
    for (int i = 0; i < 4; i++) {
        const int r = r8 + i * 8;
        tile[r][c] = src[(size_t)(k0 + r) * N + n0 + c];
    }
    __syncthreads();
#pragma unroll
    for (int i = 0; i < 4; i++) {
        const int rr = r8 + i * 8;
        dst[pidx(n0 + rr, k0 + c, K)] = f2b(tile[c][rr]);
    }
}

// four 1024x1024 weight transposes batched (wq,wk,wv -> wqkvt; wo -> wot), packed
__global__ __launch_bounds__(256) void transpose_cast4(
    const float* __restrict__ s0, const float* __restrict__ s1,
    const float* __restrict__ s2, const float* __restrict__ s3,
    unsigned short* __restrict__ wqkvt, unsigned short* __restrict__ wot) {
    __shared__ float tile[32][33];
    const int z = blockIdx.z;
    const float* src = (z == 0) ? s0 : (z == 1) ? s1 : (z == 2) ? s2 : s3;
    unsigned short* dst = (z < 3) ? wqkvt + ((size_t)z << 20) : wot;
    const int k0 = blockIdx.x * 32, n0 = blockIdx.y * 32;
    const int c = threadIdx.x & 31, r8 = threadIdx.x >> 5;
#pragma unroll
    for (int i = 0; i < 4; i++) {
        const int r = r8 + i * 8;
        tile[r][c] = src[(size_t)(k0 + r) * 1024 + n0 + c];
    }
    __syncthreads();
#pragma unroll
    for (int i = 0; i < 4; i++) {
        const int rr = r8 + i * 8;
        dst[pidx(n0 + rr, k0 + c, 1024)] = f2b(tile[c][rr]);
    }
}

// -------------------------------------------------- V -> V^T packed per (b,head)
// src: qkv V columns (rows of 3072-stride). dst: panel (b*16+h) of [64][2048],
// packed subtiles (K-depth 2048). panel stride 64*2048 = 1<<17.
__global__ __launch_bounds__(256) void vtrans_kernel(
    const unsigned short* __restrict__ src, unsigned short* __restrict__ dst) {
    __shared__ unsigned short tile[32][34];
    const int s0 = blockIdx.x * 32, hd0 = blockIdx.y * 32, b = blockIdx.z;
    const int c = threadIdx.x & 31, r8 = threadIdx.x >> 5;
#pragma unroll
    for (int i = 0; i < 4; i++) {
        const int r = r8 + i * 8;
        tile[r][c] = src[(size_t)(b * 2048 + s0 + r) * 3072 + hd0 + c];
    }
    __syncthreads();
#pragma unroll
    for (int i = 0; i < 4; i++) {
        const int rr = r8 + i * 8;
        const int g = b * 1024 + hd0 + rr;        // global hd row
        const int panel = g >> 6, local = g & 63;
        dst[((size_t)panel << 17) + pidx(local, s0 + c, 2048)] = tile[c][rr];
    }
}

// ---------------------------------------------------------------- LayerNorm
// output PACKED (K-depth 1024) - consumed only by GEMM A-staging.
__global__ __launch_bounds__(256) void ln_kernel(
    const float* __restrict__ X,
    const float* __restrict__ scale,
    const float* __restrict__ shift,
    unsigned short* __restrict__ Hout) {
    const int tok = blockIdx.x;
    const int tid = threadIdx.x;
    const size_t base = (size_t)tok * 1024 + tid * 4;
    float4 xv = *(const float4*)(X + base);
    float f[4] = {xv.x, xv.y, xv.z, xv.w};
    float s = 0.f, s2 = 0.f;
#pragma unroll
    for (int i = 0; i < 4; i++) { s += f[i]; s2 += f[i] * f[i]; }
#pragma unroll
    for (int off = 32; off >= 1; off >>= 1) {
        s += __shfl_down(s, off);
        s2 += __shfl_down(s2, off);
    }
    __shared__ float red[8];
    const int wv = tid >> 6;
    if ((tid & 63) == 0) { red[wv] = s; red[4 + wv] = s2; }
    __syncthreads();
    s = red[0] + red[1] + red[2] + red[3];
    s2 = red[4] + red[5] + red[6] + red[7];
    const float mean = s * (1.f / 1024.f);
    const float var = s2 * (1.f / 1024.f) - mean * mean;
    const float rstd = rsqrtf(var + 1e-5f);
    const float4 sc = *(const float4*)(scale + tid * 4);
    const float4 sh = *(const float4*)(shift + tid * 4);
    unsigned short ov[4];
    ov[0] = f2b((f[0] - mean) * rstd * sc.x + sh.x);
    ov[1] = f2b((f[1] - mean) * rstd * sc.y + sh.y);
    ov[2] = f2b((f[2] - mean) * rstd * sc.z + sh.z);
    ov[3] = f2b((f[3] - mean) * rstd * sc.w + sh.w);
    *(unsigned long long*)(Hout + pidx(tok, tid * 4, 1024)) = *(unsigned long long*)ov;
}

// ---------------------------------------------------------------- GEMM 128x64 (deep pipe)
// A, Bt PACKED. 256 thr / 4 waves (wave tile 64x32). NBUF=5 (60KB LDS),
// depth D=4, 3 contiguous glds16/wave/step -> steady vmcnt(9); never drains
// to 0 in the main loop (R9-verified skeleton: s_barrier + sched_barrier(0)).
// EPI: 1 = bias + residual (res row-major fp32).
template <int EPI, typename OutT>
__global__ __launch_bounds__(256) void gemm_pipe64(
    const unsigned short* __restrict__ A, const unsigned short* __restrict__ Bt,
    const float* __restrict__ bias, const float* __restrict__ res,
    OutT* __restrict__ C, int M, int N, int K) {
    constexpr int D = 4, NBUF = 5;
    __shared__ __align__(16) unsigned short As[NBUF][8 * 512];
    __shared__ __align__(16) unsigned short Bs[NBUF][4 * 512];
    const int tid = threadIdx.x;
    const int w = tid >> 6, lane = tid & 63;
    const int quad = lane >> 4, l16 = lane & 15;
    const int bm = blockIdx.x * 128, bn = blockIdx.y * 64;
    const int wm = (w & 1) * 64, wn = (w >> 1) * 32;
    const int KT = K >> 5;

    f32x4_t acc[4][2];
#pragma unroll
    for (int i = 0; i < 4; i++)
#pragma unroll
        for (int j = 0; j < 2; j++) acc[i][j] = f32x4_t{0.f, 0.f, 0.f, 0.f};

    const unsigned short* Ab = A + (((size_t)(bm >> 4) * KT) << 9) + lane * 8;
    const unsigned short* Bb = Bt + (((size_t)(bn >> 4) * KT) << 9) + lane * 8;

    // 12 subtiles (8 A + 4 B) over 4 waves -> exactly 3 contiguous glds16/wave
    auto stage = [&](int kt, int bufi) {
        glds16(Ab + ((size_t)(w * KT + kt) << 9), &As[bufi][w * 512]);
        glds16(Ab + ((size_t)((w + 4) * KT + kt) << 9), &As[bufi][(w + 4) * 512]);
        glds16(Bb + ((size_t)(w * KT + kt) << 9), &Bs[bufi][w * 512]);
    };
    auto compute = [&](int bufi) {
        bf16x8_t af[4], bfv[2];
#pragma unroll
        for (int i = 0; i < 4; i++)
            af[i] = as_bf(*(const u16x8*)&As[bufi][((wm >> 4) + i) * 512 + lane * 8]);
#pragma unroll
        for (int j = 0; j < 2; j++)
            bfv[j] = as_bf(*(const u16x8*)&Bs[bufi][((wn >> 4) + j) * 512 + lane * 8]);
#pragma unroll
        for (int i = 0; i < 4; i++)
#pragma unroll
            for (int j = 0; j < 2; j++)
                acc[i][j] = __builtin_amdgcn_mfma_f32_16x16x32_bf16(af[i], bfv[j], acc[i][j], 0, 0, 0);
    };

#pragma unroll
    for (int t = 0; t < D; ++t) stage(t, t);

    int buf = 0, sbuf = D;   // sbuf = (t+D) % NBUF
    for (int t = 0; t < KT - D; ++t) {
        wait_vm<9>();                        // tile t's 3 loads done (own wave)
        __builtin_amdgcn_s_barrier();        // everyone's tile-t loads done
        __builtin_amdgcn_sched_barrier(0);   // no ds_read hoisting above this
        stage(t + D, sbuf);
        sbuf = (sbuf + 1 == NBUF) ? 0 : sbuf + 1;
        compute(buf);
        buf = (buf + 1 == NBUF) ? 0 : buf + 1;
    }
    // tail: last D=4 tiles, decreasing in-flight counts
    wait_vm<9>(); __builtin_amdgcn_s_barrier(); __builtin_amdgcn_sched_barrier(0);
    compute(buf); buf = (buf + 1 == NBUF) ? 0 : buf + 1;
    wait_vm<6>(); __builtin_amdgcn_s_barrier(); __builtin_amdgcn_sched_barrier(0);
    compute(buf); buf = (buf + 1 == NBUF) ? 0 : buf + 1;
    wait_vm<3>(); __builtin_amdgcn_s_barrier(); __builtin_amdgcn_sched_barrier(0);
    compute(buf); buf = (buf + 1 == NBUF) ? 0 : buf + 1;
    wait_vm<0>(); __builtin_amdgcn_s_barrier(); __builtin_amdgcn_sched_barrier(0);
    compute(buf);

#pragma unroll
    for (int i = 0; i < 4; i++) {
        const int row = bm + wm + i * 16 + quad * 4;
#pragma unroll
        for (int j = 0; j < 2; j++) {
            const int col = bn + wn + j * 16 + l16;
            const float bv = bias[col];
#pragma unroll
            for (int r = 0; r < 4; r++) {
                float v = acc[i][j][r] + bv;
                if (EPI == 1) v += res[(size_t)(row + r) * N + col];
                store_out(&C[(size_t)(row + r) * N + col], v);
            }
        }
    }
}

// ---------------------------------------------------------------- GEMM 256x256 (deep pipe)
// A, Bt PACKED. 512 thr / 8 waves, NBUF=4 x 32KB A + 4 x 32KB B in ONE 128KB
// LDS pool, D=3, vmcnt(8) counted pipe (verified skeleton: s_barrier +
// sched_barrier(0), rule 18). EPI: 0 = bias, 2 = bias + exact GELU.
// PACKC: C written packed via LDS-staged coalesced copy (R17).
template <int EPI, bool PACKC, typename OutT>
__global__ __launch_bounds__(512, 2) void gemm_pipe256(
    const unsigned short* __restrict__ A, const unsigned short* __restrict__ Bt,
    const float* __restrict__ bp0, const float* __restrict__ bp1,
    const float* __restrict__ bp2, const float* __restrict__ bp3,
    OutT* __restrict__ C, int M, int N, int K) {
    constexpr int D = 3, NBUF = 4;
    __shared__ __align__(16) unsigned short lds[NBUF * 8192 * 2];   // 128 KB
#define AS17(b) (lds + (b) * 8192)
#define BS17(b) (lds + 32768 + (b) * 8192)
    const int tid = threadIdx.x;
    const int w = tid >> 6, lane = tid & 63;
    const int quad = lane >> 4, l16 = lane & 15;
    const int bm = blockIdx.x * 256, bn = blockIdx.y * 256;
    const int wm = (w & 1) * 128, wn = (w >> 1) * 64;   // 2m x 4n wave grid
    const int KT = K >> 5;

    f32x4_t acc[8][4];
#pragma unroll
    for (int i = 0; i < 8; i++)
#pragma unroll
        for (int j = 0; j < 4; j++) acc[i][j] = f32x4_t{0.f, 0.f, 0.f, 0.f};

    const unsigned short* Ab = A + (((size_t)(bm >> 4) * KT) << 9) + lane * 8;
    const unsigned short* Bb = Bt + (((size_t)(bn >> 4) * KT) << 9) + lane * 8;

    // 32 subtiles (16 A + 16 B) over 8 waves -> exactly 4 contiguous glds16/wave
    auto stage = [&](int kt, int bufi) {
        const int s0 = w * 2, s1 = s0 + 1;
        glds16(Ab + ((size_t)(s0 * KT + kt) << 9), AS17(bufi) + s0 * 512);
        glds16(Ab + ((size_t)(s1 * KT + kt) << 9), AS17(bufi) + s1 * 512);
        glds16(Bb + ((size_t)(s0 * KT + kt) << 9), BS17(bufi) + s0 * 512);
        glds16(Bb + ((size_t)(s1 * KT + kt) << 9), BS17(bufi) + s1 * 512);
    };
    auto compute = [&](int bufi) {
        bf16x8_t af[8], bfv[4];
#pragma unroll
        for (int i = 0; i < 8; i++)
            af[i] = as_bf(*(const u16x8*)(AS17(bufi) + ((wm >> 4) + i) * 512 + lane * 8));
#pragma unroll
        for (int j = 0; j < 4; j++)
            bfv[j] = as_bf(*(const u16x8*)(BS17(bufi) + ((wn >> 4) + j) * 512 + lane * 8));
#pragma unroll
        for (int i = 0; i < 8; i++)
#pragma unroll
            for (int j = 0; j < 4; j++)
                acc[i][j] = __builtin_amdgcn_mfma_f32_16x16x32_bf16(af[i], bfv[j], acc[i][j], 0, 0, 0);
    };

#pragma unroll
    for (int t = 0; t < D; ++t) stage(t, t);

    int buf = 0, sbuf = D;   // sbuf = (t+D) & 3
    for (int t = 0; t < KT - D; ++t) {
        wait_vm<8>();                        // tile t's 4 loads done (own wave)
        __builtin_amdgcn_s_barrier();        // everyone's tile-t loads done
        __builtin_amdgcn_sched_barrier(0);   // no ds_read hoisting above this
        stage(t + D, sbuf);
        sbuf = (sbuf + 1) & 3;
        compute(buf);
        buf = (buf + 1) & 3;
    }
    // tail: last D=3 tiles, decreasing in-flight counts
    wait_vm<8>(); __builtin_amdgcn_s_barrier(); __builtin_amdgcn_sched_barrier(0);
    compute(buf); buf = (buf + 1) & 3;
    wait_vm<4>(); __builtin_amdgcn_s_barrier(); __builtin_amdgcn_sched_barrier(0);
    compute(buf); buf = (buf + 1) & 3;
    wait_vm<0>(); __builtin_amdgcn_s_barrier(); __builtin_amdgcn_sched_barrier(0);
    compute(buf);

    if constexpr (PACKC) {
        // ---- R17 epilogue: packed C via LDS-staged coalesced copy
        __syncthreads();   // all waves done reading As/Bs
#pragma unroll
        for (int i = 0; i < 8; i++) {
            const int msub = (wm >> 4) + i;
#pragma unroll
            for (int j = 0; j < 4; j++) {
                const int nsub = (wn + j * 16) >> 5;
                const int col = bn + wn + j * 16 + l16;
                const int sel = col >> 10;
                const float* bp = (sel == 0) ? bp0 : (sel == 1) ? bp1 : (sel == 2) ? bp2 : bp3;
                const float bv = bp[col & 1023];
                unsigned short* dst = lds + (msub * 8 + nsub) * 512 +
                                      ((j & 1) * 2 + (l16 >> 3)) * 128 + (l16 & 7);
#pragma unroll
                for (int r = 0; r < 4; r++) {
                    float v = acc[i][j][r] + bv;
                    if (EPI == 2) v = 0.5f * v * (1.f + erff(v * 0.70710678118f));
                    dst[(quad * 4 + r) * 8] = f2b(v);
                }
            }
        }
        __syncthreads();
        // copy: 128 blocks x 1KB; thread -> (block tid>>2, quarter tid&3)
        const int blk = tid >> 2, quar = tid & 3;
        const int gm = (bm >> 4) + (blk >> 3);
        const int gn = (bn >> 5) + (blk & 7);
        unsigned short* gbase = (unsigned short*)C +
                                (((size_t)gm * (N >> 5) + gn) << 9) + quar * 128;
        const unsigned short* lbase = lds + blk * 512 + quar * 128;
#pragma unroll
        for (int c0 = 0; c0 < 16; c0++) {
            const int c = (c0 + (lane & 15)) & 15;   // rotate: spread LDS banks
            *(u16x8*)(gbase + c * 8) = *(const u16x8*)(lbase + c * 8);
        }
    } else {
#pragma unroll
        for (int i = 0; i < 8; i++) {
            const int row = bm + wm + i * 16 + quad * 4;
#pragma unroll
            for (int j = 0; j < 4; j++) {
                const int col = bn + wn + j * 16 + l16;
                const int sel = col >> 10;
                const float* bp = (sel == 0) ? bp0 : (sel == 1) ? bp1 : (sel == 2) ? bp2 : bp3;
                const float bv = bp[col & 1023];
#pragma unroll
                for (int r = 0; r < 4; r++) {
                    float v = acc[i][j][r] + bv;
                    if (EPI == 2) v = 0.5f * v * (1.f + erff(v * 0.70710678118f));
                    store_out(&C[(size_t)(row + r) * N + col], v);
                }
            }
        }
    }
#undef AS17
#undef BS17
}

// ---------------------------------------------------------------- Attention
// R20: 64 Q-rows/block (1 subtile/wave), grid (32, 32) = 1024 blocks ->
// 3 blocks/CU resident (LDS 41.5KB), 12 waves/CU. 2-buffer __syncthreads
// staging; K from qkv rows, V from packed panels; ctx PACKED out.
#define LP 68   // Ps stride (write banks 2-way max -> conflict-free)

__global__ __launch_bounds__(256, 3) void attn_kernel(
    const unsigned short* __restrict__ Q, const unsigned short* __restrict__ K,
    const unsigned short* __restrict__ Vt, unsigned short* __restrict__ O,
    int ld) {
    __shared__ __align__(16) unsigned short Ks[2][8 * 512];  // subtile jn*2+half
    __shared__ __align__(16) unsigned short Vs[2][8 * 512];  // subtile jd*2+half
    __shared__ __align__(16) unsigned short Ps[4][16 * LP];  // per-wave slab
    const int tid = threadIdx.x;
    const int w = tid >> 6, lane = tid & 63;
    const int quad = lane >> 4, l16 = lane & 15;
    const int hh = blockIdx.x >> 1, bb = blockIdx.x & 1;
    const int y = blockIdx.y;
    const int qb = (y >= 16) ? (y - 16) : (31 - y);   // pair qb with 31-qb
    const int q0 = qb * 64;
    const int tmax = qb;                              // diag tile = qb
    const size_t seqbase = (size_t)bb * 2048;
    const int hoff = hh * 64;
    const unsigned short* vtb = Vt + ((size_t)(bb * 16 + hh) << 17);
    const float cs = 0.18033688f;   // 0.125 * log2(e)

    // Q fragment: rows q0+w*16+l16, cols half*32+quad*8
    bf16x8_t qf[2];
    {
        const unsigned short* qr = Q + (seqbase + q0 + w * 16 + l16) * ld + hoff;
        qf[0] = as_bf(*(const u16x8*)(qr + quad * 8));
        qf[1] = as_bf(*(const u16x8*)(qr + 32 + quad * 8));
    }

    f32x4_t o[4];
#pragma unroll
    for (int jd = 0; jd < 4; jd++) o[jd] = f32x4_t{0.f, 0.f, 0.f, 0.f};
    float ls[4] = {0.f, 0.f, 0.f, 0.f};

    // stage tile t into buf: 16 subtile-issues, exactly 4 per wave.
    auto stage = [&](int t, int buf) {
        for (int s = w; s < 16; s += 4) {
            if (s < 8) {
                const unsigned short* src =
                    K + (seqbase + t * 64 + (s >> 1) * 16 + l16) * ld + hoff + (s & 1) * 32 + quad * 8;
                glds16(src, &Ks[buf][s * 512]);
            } else {
                const int v = s - 8;
                const unsigned short* src =
                    vtb + ((size_t)((v >> 1) * 64 + t * 2 + (v & 1)) << 9) + lane * 8;
                glds16(src, &Vs[buf][v * 512]);
            }
        }
    };

    stage(0, 0);
    __syncthreads();

    int buf = 0;
    for (int t = 0; t <= tmax; ++t) {
        if (t < tmax) stage(t + 1, buf ^ 1);

        // ---- K/V fragments for this tile
        bf16x8_t kf[4][2], vf[4][2];
#pragma unroll
        for (int jn = 0; jn < 4; jn++) {
            kf[jn][0] = as_bf(*(const u16x8*)&Ks[buf][(jn * 2 + 0) * 512 + lane * 8]);
            kf[jn][1] = as_bf(*(const u16x8*)&Ks[buf][(jn * 2 + 1) * 512 + lane * 8]);
            vf[jn][0] = as_bf(*(const u16x8*)&Vs[buf][(jn * 2 + 0) * 512 + lane * 8]);
            vf[jn][1] = as_bf(*(const u16x8*)&Vs[buf][(jn * 2 + 1) * 512 + lane * 8]);
        }

        // ---- S = Q@K^T, exp2, deferred sum, P->LDS  (no cross-lane ops)
        {
            const bool diag = (t == tmax);
#pragma unroll
            for (int jn = 0; jn < 4; jn++) {
                f32x4_t z = f32x4_t{0.f, 0.f, 0.f, 0.f};
                z = __builtin_amdgcn_mfma_f32_16x16x32_bf16(qf[0], kf[jn][0], z, 0, 0, 0);
                z = __builtin_amdgcn_mfma_f32_16x16x32_bf16(qf[1], kf[jn][1], z, 0, 0, 0);
#pragma unroll
                for (int r = 0; r < 4; r++) {
                    float p = exp2f(fminf(z[r] * cs, 60.f));
                    if (diag) {
                        const int col = t * 64 + jn * 16 + l16;
                        const int row = q0 + w * 16 + quad * 4 + r;
                        p = (col <= row) ? p : 0.f;
                    }
                    ls[r] += p;
                    Ps[w][(quad * 4 + r) * LP + jn * 16 + l16] = f2b(p);
                }
            }
        }

        // ---- O += P @ V  (wave-private P slab, no barrier needed)
        {
            const bf16x8_t pf0 = as_bf(*(const u16x8*)&Ps[w][l16 * LP + quad * 8]);
            const bf16x8_t pf1 = as_bf(*(const u16x8*)&Ps[w][l16 * LP + 32 + quad * 8]);
#pragma unroll
            for (int jd = 0; jd < 4; jd++) {
                o[jd] = __builtin_amdgcn_mfma_f32_16x16x32_bf16(pf0, vf[jd][0], o[jd], 0, 0, 0);
                o[jd] = __builtin_amdgcn_mfma_f32_16x16x32_bf16(pf1, vf[jd][1], o[jd], 0, 0, 0);
            }
        }
        __syncthreads();   // drains glds(t+1); all waves done with buf
        buf ^= 1;
    }

    // ---- epilogue: one cross-lane reduction per row, packed ctx store
#pragma unroll
    for (int r = 0; r < 4; r++) {
        float s = ls[r];
        s += __shfl_xor(s, 1);
        s += __shfl_xor(s, 2);
        s += __shfl_xor(s, 4);
        s += __shfl_xor(s, 8);
        const float inv = 1.f / s;
        const int row = (int)seqbase + q0 + w * 16 + quad * 4 + r;
#pragma unroll
        for (int jd = 0; jd < 4; jd++)
            O[pidx(row, hoff + jd * 16 + l16, 1024)] = f2b(o[jd][r] * inv);
    }
}

// ---------------------------------------------------------------- launch
extern "C" void kernel_launch(void* const* d_in, const int* in_sizes, int n_in,
                              void* d_out, int out_size, void* d_ws, size_t ws_size,
                              hipStream_t stream) {
    const float* x = (const float*)d_in[0];
    const float* ln1s = (const float*)d_in[1];
    const float* ln1b = (const float*)d_in[2];
    const float* ln2s = (const float*)d_in[3];
    const float* ln2b = (const float*)d_in[4];
    const float* wq = (const float*)d_in[5];
    const float* bq = (const float*)d_in[6];
    const float* wk = (const float*)d_in[7];
    const float* bk = (const float*)d_in[8];
    const float* wv = (const float*)d_in[9];
    const float* bv = (const float*)d_in[10];
    const float* wo = (const float*)d_in[11];
    const float* bo = (const float*)d_in[12];
    const float* w1 = (const float*)d_in[13];
    const float* b1 = (const float*)d_in[14];
    const float* w2 = (const float*)d_in[15];
    const float* b2 = (const float*)d_in[16];
    float* out = (float*)d_out;

    char* ws = (char*)d_ws;
    const size_t MB = 1u << 20;
    unsigned short* wqkvt = (unsigned short*)(ws + 0 * MB);
    unsigned short* wot   = (unsigned short*)(ws + 6 * MB);
    unsigned short* w1t   = (unsigned short*)(ws + 8 * MB);
    unsigned short* w2t   = (unsigned short*)(ws + 16 * MB);
    unsigned short* h     = (unsigned short*)(ws + 24 * MB);
    unsigned short* vt    = (unsigned short*)(ws + 24 * MB);
    unsigned short* qkv   = (unsigned short*)(ws + 32 * MB);
    unsigned short* ctx   = (unsigned short*)(ws + 56 * MB);
    unsigned short* h2    = (unsigned short*)(ws + 24 * MB);
    float*          x1    = (float*)(ws + 64 * MB);
    unsigned short* g     = (unsigned short*)(ws + 32 * MB);

    const dim3 blk(256);

    transpose_cast4<<<dim3(32, 32, 4), blk, 0, stream>>>(wq, wk, wv, wo, wqkvt, wot);
    transpose_cast<<<dim3(32, 128), blk, 0, stream>>>(w1, w1t, 1024, 4096);
    transpose_cast<<<dim3(128, 32), blk, 0, stream>>>(w2, w2t, 4096, 1024);

    ln_kernel<<<4096, blk, 0, stream>>>(x, ln1s, ln1b, h);
    // qkv GEMM: 256x256 deep pipe (A,B packed; C row-major for attn)
    gemm_pipe256<0, false, unsigned short><<<dim3(16, 12), dim3(512), 0, stream>>>(
        h, wqkvt, bq, bk, bv, bv, qkv, 4096, 3072, 1024);
    vtrans_kernel<<<dim3(64, 32, 2), blk, 0, stream>>>(qkv + 2048, vt);
    // attn: 64-row blocks, grid (32,32) = 1024 blocks (R20)
    attn_kernel<<<dim3(32, 32), blk, 0, stream>>>(qkv, qkv + 1024, vt, ctx, 3072);
    // wo GEMM: counted-vmcnt deep pipe, packed loads (R21)
    gemm_pipe64<1, float><<<dim3(32, 16), blk, 0, stream>>>(
        ctx, wot, bo, x, x1, 4096, 1024, 1024);
    ln_kernel<<<4096, blk, 0, stream>>>(x1, ln2s, ln2b, h2);
    // w1 GEMM: 256x256 deep pipe + GELU (A=h2 packed, B packed, C=g PACKED
    // via LDS-staged coalesced store - R17)
    gemm_pipe256<2, true, unsigned short><<<dim3(16, 16), dim3(512), 0, stream>>>(
        h2, w1t, b1, b1 + 1024, b1 + 2048, b1 + 3072, g, 4096, 4096, 1024);
    // w2 GEMM: counted-vmcnt deep pipe, packed loads (R21)
    gemm_pipe64<1, float><<<dim3(32, 16), blk, 0, stream>>>(
        g, w2t, b2, x1, out, 4096, 1024, 4096);
}